// Round 17
// baseline (233.952 us; speedup 1.0000x reference)
//
#include <hip/hip_runtime.h>
#include <math.h>
#include <stdint.h>

static constexpr int B  = 8;
static constexpr int T  = 256;
static constexpr int C  = 1024;
static constexpr int H  = 16;
static constexpr int HEAD = 64;
static constexpr int FF = 4096;
static constexpr int BT = B * T;
static constexpr int NCH = 8;       // time chunks
static constexpr int CS  = 32;      // chunk size (NCH*CS == T)

typedef short short8  __attribute__((ext_vector_type(8)));
typedef float floatx4 __attribute__((ext_vector_type(4)));

// ---------------- bf16 helpers ----------------
__device__ __forceinline__ float bf2f(ushort u) {
    return __uint_as_float(((uint32_t)u) << 16);
}
__device__ __forceinline__ ushort f2bf(float x) {
    uint32_t u = __float_as_uint(x);
    u += 0x7fff + ((u >> 16) & 1);          // RNE
    return (ushort)(u >> 16);
}

__device__ __forceinline__ void gload16(const void* g, void* l) {
    __builtin_amdgcn_global_load_lds(
        (const __attribute__((address_space(1))) unsigned int*)g,
        (__attribute__((address_space(3))) unsigned int*)l, 16, 0, 0);
}

// ---------------- epilogue ids ----------------
#define BEPI_NONE_BF   0
#define BEPI_SILU_BF   1
#define BEPI_RELUSQ_BF 2
#define BEPI_NONE_F    3
#define BEPI_RES_F     4
#define BEPI_SIGRES_F  5
#define BEPI_TANH_F    6
#define BEPI_TANH_BF   7
#define BEPI_DECAY_F   8
#define BEPI_SIGRES2_F 9

// ---- 3-row LN helper: reduce 6 partial sums across block ----
__device__ __forceinline__ void red6(float (&vals)[6], float* red)
{
    const int wave = threadIdx.x >> 6, lane = threadIdx.x & 63;
#pragma unroll
    for (int i = 0; i < 6; ++i) {
        float v = vals[i];
#pragma unroll
        for (int off = 32; off > 0; off >>= 1) v += __shfl_xor(v, off);
        if (lane == 0) red[i * 4 + wave] = v;
    }
    __syncthreads();
#pragma unroll
    for (int i = 0; i < 6; ++i)
        vals[i] = red[i * 4 + 0] + red[i * 4 + 1] + red[i * 4 + 2] + red[i * 4 + 3];
}

// ---- fused LN + bshift + mixax (attention); xa/xx now bf16 ----
__global__ __launch_bounds__(256) void lnshiftmix_kernel(const float* __restrict__ x,
                                                         const float* __restrict__ g,
                                                         const float* __restrict__ b,
                                                         const float* __restrict__ maa,
                                                         ushort* __restrict__ xa,
                                                         ushort* __restrict__ xx,
                                                         ushort* __restrict__ ax)
{
    const int row = blockIdx.x;
    const int t = row & (T - 1);
    const int tid = threadIdx.x;
    __shared__ float red[24];
    const float4 vc = reinterpret_cast<const float4*>(x + (size_t)row * C)[tid];
    float4 vp = make_float4(0.f, 0.f, 0.f, 0.f), vn = make_float4(0.f, 0.f, 0.f, 0.f);
    if (t > 0)     vp = reinterpret_cast<const float4*>(x + (size_t)(row - 1) * C)[tid];
    if (t < T - 1) vn = reinterpret_cast<const float4*>(x + (size_t)(row + 1) * C)[tid];
    float vals[6];
    vals[0] = vc.x + vc.y + vc.z + vc.w;
    vals[1] = vc.x * vc.x + vc.y * vc.y + vc.z * vc.z + vc.w * vc.w;
    vals[2] = vp.x + vp.y + vp.z + vp.w;
    vals[3] = vp.x * vp.x + vp.y * vp.y + vp.z * vp.z + vp.w * vp.w;
    vals[4] = vn.x + vn.y + vn.z + vn.w;
    vals[5] = vn.x * vn.x + vn.y * vn.y + vn.z * vn.z + vn.w * vn.w;
    red6(vals, red);
    const float mc = vals[0] * (1.f / C);
    const float rc = rsqrtf(fmaxf(vals[1] * (1.f / C) - mc * mc, 0.f) + 1e-5f);
    const float mp = vals[2] * (1.f / C);
    const float rp = rsqrtf(fmaxf(vals[3] * (1.f / C) - mp * mp, 0.f) + 1e-5f);
    const float mn = vals[4] * (1.f / C);
    const float rn = rsqrtf(fmaxf(vals[5] * (1.f / C) - mn * mn, 0.f) + 1e-5f);

    const int c = tid * 4;
    const bool fh = ((c & 63) < 32);
    const float cur[4] = {vc.x, vc.y, vc.z, vc.w};
    const float nbr[4] = {fh ? vp.x : vn.x, fh ? vp.y : vn.y,
                          fh ? vp.z : vn.z, fh ? vp.w : vn.w};
    const float mN = fh ? mp : mn, rN = fh ? rp : rn;
    const bool nvalid = fh ? (t > 0) : (t < T - 1);
    const size_t rb = (size_t)row * C;
#pragma unroll
    for (int e = 0; e < 4; ++e) {
        const float gg = g[c + e], bb = b[c + e];
        const float av = (cur[e] - mc) * rc * gg + bb;
        const float sv = nvalid ? ((nbr[e] - mN) * rN * gg + bb) : 0.f;
        const float xv = sv - av;
        xa[rb + c + e] = f2bf(av);
        xx[rb + c + e] = f2bf(xv);
        ax[rb + c + e] = f2bf(av + xv * maa[c + e]);
    }
}

// ---- fused LN + bshift + cmix (FFN) ----
__global__ __launch_bounds__(256) void lnshiftcmix_kernel(const float* __restrict__ x,
                                                          const float* __restrict__ g,
                                                          const float* __restrict__ b,
                                                          const float* __restrict__ mk,
                                                          const float* __restrict__ mr,
                                                          ushort* __restrict__ ok,
                                                          ushort* __restrict__ orr)
{
    const int row = blockIdx.x;
    const int t = row & (T - 1);
    const int tid = threadIdx.x;
    __shared__ float red[24];
    const float4 vc = reinterpret_cast<const float4*>(x + (size_t)row * C)[tid];
    float4 vp = make_float4(0.f, 0.f, 0.f, 0.f), vn = make_float4(0.f, 0.f, 0.f, 0.f);
    if (t > 0)     vp = reinterpret_cast<const float4*>(x + (size_t)(row - 1) * C)[tid];
    if (t < T - 1) vn = reinterpret_cast<const float4*>(x + (size_t)(row + 1) * C)[tid];
    float vals[6];
    vals[0] = vc.x + vc.y + vc.z + vc.w;
    vals[1] = vc.x * vc.x + vc.y * vc.y + vc.z * vc.z + vc.w * vc.w;
    vals[2] = vp.x + vp.y + vp.z + vp.w;
    vals[3] = vp.x * vp.x + vp.y * vp.y + vp.z * vp.z + vp.w * vp.w;
    vals[4] = vn.x + vn.y + vn.z + vn.w;
    vals[5] = vn.x * vn.x + vn.y * vn.y + vn.z * vn.z + vn.w * vn.w;
    red6(vals, red);
    const float mc = vals[0] * (1.f / C);
    const float rc = rsqrtf(fmaxf(vals[1] * (1.f / C) - mc * mc, 0.f) + 1e-5f);
    const float mp = vals[2] * (1.f / C);
    const float rp = rsqrtf(fmaxf(vals[3] * (1.f / C) - mp * mp, 0.f) + 1e-5f);
    const float mn = vals[4] * (1.f / C);
    const float rn = rsqrtf(fmaxf(vals[5] * (1.f / C) - mn * mn, 0.f) + 1e-5f);

    const int c = tid * 4;
    const bool fh = ((c & 63) < 32);
    const float cur[4] = {vc.x, vc.y, vc.z, vc.w};
    const float nbr[4] = {fh ? vp.x : vn.x, fh ? vp.y : vn.y,
                          fh ? vp.z : vn.z, fh ? vp.w : vn.w};
    const float mN = fh ? mp : mn, rN = fh ? rp : rn;
    const bool nvalid = fh ? (t > 0) : (t < T - 1);
    const size_t rb = (size_t)row * C;
#pragma unroll
    for (int e = 0; e < 4; ++e) {
        const float gg = g[c + e], bb = b[c + e];
        const float av = (cur[e] - mc) * rc * gg + bb;
        const float sv = nvalid ? ((nbr[e] - mN) * rN * gg + bb) : 0.f;
        const float xv = sv - av;
        ok[rb + c + e]  = f2bf(av + xv * mk[c + e]);
        orr[rb + c + e] = f2bf(av + xv * mr[c + e]);
    }
}

// -------- GroupNorm(yf+yb+sig*v)*g+b, * gate; u-bonus scalar fused ---------
__global__ __launch_bounds__(1024) void gnmul_kernel(const ushort* __restrict__ yf,
                                                     const ushort* __restrict__ yb,
                                                     const float* __restrict__ g,
                                                     const float* __restrict__ b,
                                                     const ushort* __restrict__ gate,
                                                     const ushort* __restrict__ vin,
                                                     const ushort* __restrict__ rbuf,
                                                     const ushort* __restrict__ kbuf,
                                                     const float* __restrict__ u,
                                                     ushort* __restrict__ out)
{
    const int row = blockIdx.x;
    const int tid = threadIdx.x;                 // wave == head
    const size_t idx = (size_t)row * C + tid;
    float p = bf2f(rbuf[idx]) * bf2f(kbuf[idx]) * u[tid];
#pragma unroll
    for (int off = 32; off > 0; off >>= 1) p += __shfl_xor(p, off);
    const float v = bf2f(yf[idx]) + bf2f(yb[idx]) + p * bf2f(vin[idx]);
    float s = v;
#pragma unroll
    for (int off = 32; off > 0; off >>= 1) s += __shfl_xor(s, off);
    const float m = s * (1.0f / HEAD);
    const float d = v - m;
    float q = d * d;
#pragma unroll
    for (int off = 32; off > 0; off >>= 1) q += __shfl_xor(q, off);
    const float rstd = rsqrtf(q * (1.0f / HEAD) + 6.4e-4f);
    out[idx] = f2bf((d * rstd * g[tid] + b[tid]) * bf2f(gate[idx]));
}

// -------- batched weight convert+transpose: up to 8 jobs, one launch --------
struct WJobs {
    const float* W[8];
    ushort* dst[8];
    int Kd[8], Nd[8], ntx[8], base[8];
    int njobs;
};
__global__ __launch_bounds__(256) void wconvB_kernel(WJobs jobs)
{
    __shared__ float tile[32][33];
    const int bid = blockIdx.x;
    int j = 0;
#pragma unroll
    for (int i = 1; i < 8; ++i)
        if (i < jobs.njobs && bid >= jobs.base[i]) j = i;
    const float* __restrict__ W = jobs.W[j];
    ushort* __restrict__ dst = jobs.dst[j];
    const int Kd = jobs.Kd[j], Nd = jobs.Nd[j];
    const int local = bid - jobs.base[j];
    const int n0 = (local % jobs.ntx[j]) * 32;
    const int k0 = (local / jobs.ntx[j]) * 32;
    const int tx = threadIdx.x, ty = threadIdx.y;
#pragma unroll
    for (int i = 0; i < 4; ++i)
        tile[ty * 4 + i][tx] = W[(size_t)(k0 + ty * 4 + i) * Nd + n0 + tx];
    __syncthreads();
#pragma unroll
    for (int i = 0; i < 4; ++i)
        dst[(size_t)(n0 + ty * 4 + i) * Kd + k0 + tx] = f2bf(tile[tx][ty * 4 + i]);
}

// -------- batched wconv: 4 C x C weights (blockIdx.z) --------
struct Wconv4Args { const float* W[4]; };
__global__ __launch_bounds__(256) void wconv4_kernel(Wconv4Args args, ushort* __restrict__ Wt)
{
    __shared__ float tile[32][33];
    const int z = blockIdx.z;
    const float* __restrict__ W = args.W[z];
    ushort* __restrict__ dst = Wt + (size_t)z * C * C;
    const int n0 = blockIdx.x * 32, k0 = blockIdx.y * 32;
    const int tx = threadIdx.x, ty = threadIdx.y;
#pragma unroll
    for (int i = 0; i < 4; ++i)
        tile[ty * 4 + i][tx] = W[(size_t)(k0 + ty * 4 + i) * C + n0 + tx];
    __syncthreads();
#pragma unroll
    for (int i = 0; i < 4; ++i)
        dst[(size_t)(n0 + ty * 4 + i) * C + k0 + tx] = f2bf(tile[tx][ty * 4 + i]);
}

// ======== mix5 as fused MFMA GEMM (xa/xx bf16) ========
struct Mix5Args { const float* maa[5]; ushort* out[5]; };
__global__ __launch_bounds__(256) void mix5m_kernel(const ushort* __restrict__ a5b,
                                                    const ushort* __restrict__ w2t,
                                                    const ushort* __restrict__ xa,
                                                    const ushort* __restrict__ xx,
                                                    Mix5Args args)
{
    __shared__ __align__(16) ushort As[128 * 32];
    __shared__ __align__(16) ushort Bs[64 * 32];
    const int f = blockIdx.z;
    const int bm = blockIdx.y * 128, bn = blockIdx.x * 64;
    const int tid = threadIdx.x;
    const int wid = tid >> 6, lane = tid & 63;
    const int wr = wid >> 1, wc = wid & 1;
    const int l15 = lane & 15, lhi = lane >> 4;

#pragma unroll
    for (int p = 0; p < 2; ++p) {
        const int lin = p * 256 + tid;
        const int row = lin >> 2;
        const int sp = (lin & 3) ^ ((row >> 1) & 3);
        gload16(a5b + (size_t)(bm + row) * 160 + f * 32 + sp * 8, &As[lin * 8]);
    }
    {
        const int lin = tid;
        const int n = lin >> 2;
        const int sp = (lin & 3) ^ ((n >> 1) & 3);
        gload16(w2t + ((size_t)f * C + bn + n) * 32 + sp * 8, &Bs[lin * 8]);
    }
    __syncthreads();

    short8 af[4], bfr[2];
#pragma unroll
    for (int m = 0; m < 4; ++m) {
        const int row = wr * 64 + m * 16 + l15;
        const int sp = lhi ^ ((row >> 1) & 3);
        af[m] = *(const short8*)&As[row * 32 + sp * 8];
    }
#pragma unroll
    for (int n = 0; n < 2; ++n) {
        const int col = wc * 32 + n * 16 + l15;
        const int sp = lhi ^ ((col >> 1) & 3);
        bfr[n] = *(const short8*)&Bs[col * 32 + sp * 8];
    }
    floatx4 acc[4][2];
#pragma unroll
    for (int m = 0; m < 4; ++m)
#pragma unroll
        for (int n = 0; n < 2; ++n)
            acc[m][n] = __builtin_amdgcn_mfma_f32_16x16x32_bf16(
                af[m], bfr[n], (floatx4){0.f, 0.f, 0.f, 0.f}, 0, 0, 0);

    const float* __restrict__ maa = args.maa[f];
    ushort* __restrict__ out = args.out[f];
#pragma unroll
    for (int m = 0; m < 4; ++m) {
        const int row0 = bm + wr * 64 + m * 16 + lhi * 4;
#pragma unroll
        for (int n = 0; n < 2; ++n) {
            const int col = bn + wc * 32 + n * 16 + l15;
            const float mc = maa[col];
#pragma unroll
            for (int j = 0; j < 4; ++j) {
                const size_t oi = (size_t)(row0 + j) * C + col;
                out[oi] = f2bf(bf2f(xa[oi]) + bf2f(xx[oi]) * (mc + acc[m][n][j]));
            }
        }
    }
}

// ================== chunked bidirectional WKV6 (MFMA) ==================
__global__ __launch_bounds__(256) void wkv_pass1(const ushort* __restrict__ k,
                                                 const ushort* __restrict__ v,
                                                 const float* __restrict__ d,
                                                 ushort* __restrict__ M,
                                                 float* __restrict__ D)
{
    const int uc = blockIdx.x;
    const int c = uc & (NCH - 1), unit = uc >> 3;
    const int dir = unit & 1, bh = unit >> 1;
    const int tid = threadIdx.x;
    const int wv = tid >> 6, lane = tid & 63;
    const int l15 = lane & 15, lhi = lane >> 4;
    const size_t rowb = ((size_t)(bh >> 4) * T * H + (bh & 15)) * HEAD;
    const int s0 = c * CS;

    __shared__ ushort kT[64][40];
    __shared__ ushort vt[64][40];
    __shared__ float  Ldd[CS][64];

    for (int idx = tid; idx < CS * 64; idx += 256) {
        const int s = idx >> 6, j = idx & 63;
        const int t = dir ? (T - 1 - (s0 + s)) : (s0 + s);
        const size_t g = rowb + (size_t)t * (H * HEAD) + j;
        kT[j][s] = k[g];
        vt[j][s] = v[g];
        Ldd[s][j] = d[g];
    }
    __syncthreads();

    if (tid < 64) {
        const int j = tid;
        float G = 1.f;
#pragma unroll
        for (int s = CS - 1; s >= 0; --s) {
            kT[j][s] = f2bf(bf2f(kT[j][s]) * G);
            G *= Ldd[s][j];
        }
        D[(size_t)uc * 64 + j] = G;
    }
    __syncthreads();

    const short8 av = *(const short8*)&vt[wv * 16 + l15][lhi * 8];
    ushort* __restrict__ mrow = M + (size_t)uc * 4096;
#pragma unroll
    for (int n = 0; n < 4; ++n) {
        const short8 bk = *(const short8*)&kT[n * 16 + l15][lhi * 8];
        const floatx4 acc = __builtin_amdgcn_mfma_f32_16x16x32_bf16(
            av, bk, (floatx4){0.f, 0.f, 0.f, 0.f}, 0, 0, 0);
#pragma unroll
        for (int jr = 0; jr < 4; ++jr) {
            const int i = wv * 16 + lhi * 4 + jr;
            mrow[(size_t)i * 64 + n * 16 + l15] = f2bf(acc[jr]);
        }
    }
}

// pass2: prefetch all 8 chunk M/D values (independent), then 8 local steps.
__global__ __launch_bounds__(1024) void wkv_pass2(ushort* __restrict__ M,
                                                  const float* __restrict__ D)
{
    const int unit = blockIdx.x;
    const int tid = threadIdx.x;
    const int j0 = (tid & 15) * 4;
    uint2 mv[NCH];
    float4 Dv[NCH];
#pragma unroll
    for (int c = 0; c < NCH; ++c) {
        const int uc = unit * NCH + c;
        mv[c] = *reinterpret_cast<const uint2*>(M + (size_t)uc * 4096 + tid * 4);
        Dv[c] = *reinterpret_cast<const float4*>(D + (size_t)uc * 64 + j0);
    }
    float S0 = 0.f, S1 = 0.f, S2 = 0.f, S3 = 0.f;
#pragma unroll
    for (int c = 0; c < NCH; ++c) {
        const int uc = unit * NCH + c;
        uint2 sv;
        sv.x = (uint32_t)f2bf(S0) | ((uint32_t)f2bf(S1) << 16);
        sv.y = (uint32_t)f2bf(S2) | ((uint32_t)f2bf(S3) << 16);
        *reinterpret_cast<uint2*>(M + (size_t)uc * 4096 + tid * 4) = sv;
        S0 = fmaf(Dv[c].x, S0, bf2f((ushort)(mv[c].x & 0xffff)));
        S1 = fmaf(Dv[c].y, S1, bf2f((ushort)(mv[c].x >> 16)));
        S2 = fmaf(Dv[c].z, S2, bf2f((ushort)(mv[c].y & 0xffff)));
        S3 = fmaf(Dv[c].w, S3, bf2f((ushort)(mv[c].y >> 16)));
    }
}

__global__ __launch_bounds__(256) void wkv_ymfma(const ushort* __restrict__ r,
                                                 const ushort* __restrict__ k,
                                                 const ushort* __restrict__ v,
                                                 const float* __restrict__ d,
                                                 const ushort* __restrict__ Sin,
                                                 ushort* __restrict__ yf,
                                                 ushort* __restrict__ yb)
{
    const int uc = blockIdx.x;
    const int c = uc & (NCH - 1), unit = uc >> 3;
    const int dir = unit & 1, bh = unit >> 1;
    const int tid = threadIdx.x;
    const int wv = tid >> 6, lane = tid & 63;
    const int l15 = lane & 15, lhi = lane >> 4;
    const size_t rowb = ((size_t)(bh >> 4) * T * H + (bh & 15)) * HEAD;
    const int s0 = c * CS;

    __shared__ ushort rp[32][64];
    __shared__ ushort kp[32][64];
    __shared__ ushort vt[64][40];
    __shared__ ushort Pl[32][32];
    __shared__ float  Ldd[CS][64];

    for (int idx = tid; idx < 32 * 64; idx += 256) {
        const int s = idx >> 6, j = idx & 63;
        const int t = dir ? (T - 1 - (s0 + s)) : (s0 + s);
        const size_t g = rowb + (size_t)t * (H * HEAD) + j;
        const int cs = (j >> 3) ^ (s & 7);
        rp[s][cs * 8 + (j & 7)] = r[g];
        kp[s][cs * 8 + (j & 7)] = k[g];
        vt[j][s] = v[g];
        Ldd[s][j] = d[g];
    }
    __syncthreads();

    if (wv == 0) {                   // r' = r * Q[s]
        const int j = lane;
        float Q = 1.f;
#pragma unroll
        for (int s = 0; s < 32; ++s) {
            const int a = ((j >> 3) ^ (s & 7)) * 8 + (j & 7);
            rp[s][a] = f2bf(bf2f(rp[s][a]) * Q);
            Q *= Ldd[s][j];
        }
    } else if (wv == 1) {            // k' = k / Q[s+1]
        const int j = lane;
        float iQ = 1.f;
#pragma unroll
        for (int s = 0; s < 32; ++s) {
            iQ *= (1.0f / Ldd[s][j]);
            const int a = ((j >> 3) ^ (s & 7)) * 8 + (j & 7);
            kp[s][a] = f2bf(bf2f(kp[s][a]) * iQ);
        }
    }
    __syncthreads();

    const int st = wv & 1;
    const int ip = wv >> 1;

    short8 ar[2];
#pragma unroll
    for (int ks = 0; ks < 2; ++ks) {
        const int row = st * 16 + l15;
        const int ch = (ks * 4 + lhi) ^ (row & 7);
        ar[ks] = *(const short8*)&rp[row][ch * 8];
    }

    floatx4 acc[2];
#pragma unroll
    for (int n = 0; n < 2; ++n) {
        const int i = ip * 32 + n * 16 + l15;
        const ushort* sp = Sin + (size_t)uc * 4096 + (size_t)i * 64;
        const short8 b0 = *(const short8*)&sp[lhi * 8];
        const short8 b1 = *(const short8*)&sp[32 + lhi * 8];
        acc[n] = __builtin_amdgcn_mfma_f32_16x16x32_bf16(ar[0], b0, (floatx4){0.f, 0.f, 0.f, 0.f}, 0, 0, 0);
        acc[n] = __builtin_amdgcn_mfma_f32_16x16x32_bf16(ar[1], b1, acc[n], 0, 0, 0);
    }

    if (wv < 2) {
#pragma unroll
        for (int ut = 0; ut < 2; ++ut) {
            const int urow = ut * 16 + l15;
            const short8 bk0 = *(const short8*)&kp[urow][((0 + lhi) ^ (urow & 7)) * 8];
            const short8 bk1 = *(const short8*)&kp[urow][((4 + lhi) ^ (urow & 7)) * 8];
            floatx4 pa = __builtin_amdgcn_mfma_f32_16x16x32_bf16(ar[0], bk0, (floatx4){0.f, 0.f, 0.f, 0.f}, 0, 0, 0);
            pa = __builtin_amdgcn_mfma_f32_16x16x32_bf16(ar[1], bk1, pa, 0, 0, 0);
            const int sg0 = st * 16 + lhi * 4;
            const int ug = ut * 16 + l15;
#pragma unroll
            for (int jr = 0; jr < 4; ++jr) {
                const float val = (ug < sg0 + jr) ? pa[jr] : 0.f;
                Pl[sg0 + jr][ug] = f2bf(val);
            }
        }
    }
    __syncthreads();

    short8 ap;
    {
        const int row = st * 16 + l15;
        ap = *(const short8*)&Pl[row][lhi * 8];
    }
#pragma unroll
    for (int n = 0; n < 2; ++n) {
        const int i = ip * 32 + n * 16 + l15;
        const short8 bv = *(const short8*)&vt[i][lhi * 8];
        acc[n] = __builtin_amdgcn_mfma_f32_16x16x32_bf16(ap, bv, acc[n], 0, 0, 0);
    }

    ushort* __restrict__ yo = dir ? yb : yf;
#pragma unroll
    for (int n = 0; n < 2; ++n) {
        const int i = ip * 32 + n * 16 + l15;
#pragma unroll
        for (int jr = 0; jr < 4; ++jr) {
            const int sg = st * 16 + lhi * 4 + jr;
            const int t = dir ? (T - 1 - (s0 + sg)) : (s0 + sg);
            yo[rowb + (size_t)t * (H * HEAD) + i] = f2bf(acc[n][jr]);
        }
    }
}

// ======== pipelined bf16 MFMA GEMM core: 8 waves (512 thr), BM=128, BK=64 ======
template <int BN>
struct GemmLds {
    ushort As[2][128 * 64];
    ushort Bs[2][BN * 64];
};

template <int BN>
__device__ __forceinline__ void gemm_body8(const ushort* __restrict__ A,
                                           const ushort* __restrict__ Bt,
                                           int bm, int bn, int K, int lda, int ldb,
                                           GemmLds<BN>& lds,
                                           floatx4 (&acc)[4][BN / 64])
{
    constexpr int NF = BN / 64;
    const int tid = threadIdx.x;                 // 512
    const int wid = tid >> 6, lane = tid & 63;
    const int wr = wid >> 2, wc = wid & 3;
    const int l15 = lane & 15, lhi = lane >> 4;
    const int NT = K >> 6;

    auto stage = [&](int buf, int k0) {
#pragma unroll
        for (int p = 0; p < 2; ++p) {
            const int lin = p * 512 + tid;
            const int row = lin >> 3;
            const int cs = (lin & 7) ^ (row & 7);
            gload16(A + (size_t)(bm + row) * lda + k0 + cs * 8, &lds.As[buf][lin * 8]);
        }
#pragma unroll
        for (int p = 0; p < NF; ++p) {
            const int lin = p * 512 + tid;
            const int n = lin >> 3;
            const int cs = (lin & 7) ^ (n & 7);
            gload16(Bt + (size_t)(bn + n) * ldb + k0 + cs * 8, &lds.Bs[buf][lin * 8]);
        }
    };

    stage(0, 0);
    __syncthreads();
    for (int t = 0; t < NT; ++t) {
        const int cur = t & 1;
        if (t + 1 < NT) stage(cur ^ 1, (t + 1) << 6);

        short8 af[4][2];
#pragma unroll
        for (int m = 0; m < 4; ++m) {
            const int row = wr * 64 + m * 16 + l15;
#pragma unroll
            for (int s = 0; s < 2; ++s) {
                const int cc = (s * 4 + lhi) ^ (row & 7);
                af[m][s] = *(const short8*)&lds.As[cur][row * 64 + cc * 8];
            }
        }
        short8 bf[NF][2];
#pragma unroll
        for (int n = 0; n < NF; ++n) {
            const int col = wc * (BN / 4) + n * 16 + l15;
#pragma unroll
            for (int s = 0; s < 2; ++s) {
                const int cc = (s * 4 + lhi) ^ (col & 7);
                bf[n][s] = *(const short8*)&lds.Bs[cur][col * 64 + cc * 8];
            }
        }
#pragma unroll
        for (int m = 0; m < 4; ++m)
#pragma unroll
            for (int n = 0; n < NF; ++n) {
                acc[m][n] = __builtin_amdgcn_mfma_f32_16x16x32_bf16(af[m][0], bf[n][0], acc[m][n], 0, 0, 0);
                acc[m][n] = __builtin_amdgcn_mfma_f32_16x16x32_bf16(af[m][1], bf[n][1], acc[m][n], 0, 0, 0);
            }
        __syncthreads();
    }
}

template <int BN, int EPI>
__global__ __launch_bounds__(512) void bgemm_kernel(const ushort* __restrict__ A,
                                                    const ushort* __restrict__ Bt,
                                                    void* __restrict__ Cm,
                                                    int M, int N, int K,
                                                    const float* __restrict__ aux1,
                                                    const float* __restrict__ aux2,
                                                    const float* __restrict__ aux3)
{
    constexpr int NF = BN / 64;
    __shared__ GemmLds<BN> lds;
    int w = blockIdx.y * gridDim.x + blockIdx.x;
    const int nwg = gridDim.x * gridDim.y;
    if ((nwg & 7) == 0) w = (w & 7) * (nwg >> 3) + (w >> 3);   // XCD swizzle
    const int bn = (w % gridDim.x) * BN;
    const int bm = (w / gridDim.x) * 128;
    const int tid = threadIdx.x;
    const int wid = tid >> 6, lane = tid & 63;
    const int wr = wid >> 2, wc = wid & 3;
    const int l15 = lane & 15, lhi = lane >> 4;

    floatx4 acc[4][NF];
#pragma unroll
    for (int m = 0; m < 4; ++m)
#pragma unroll
        for (int n = 0; n < NF; ++n) acc[m][n] = (floatx4){0.f, 0.f, 0.f, 0.f};

    gemm_body8<BN>(A, Bt, bm, bn, K, K, K, lds, acc);

#pragma unroll
    for (int m = 0; m < 4; ++m) {
        const int row0 = bm + wr * 64 + m * 16 + lhi * 4;
#pragma unroll
        for (int n = 0; n < NF; ++n) {
            const int col = bn + wc * (BN / 4) + n * 16 + l15;
            if (col >= N) continue;
#pragma unroll
            for (int j = 0; j < 4; ++j) {
                const size_t oi = (size_t)(row0 + j) * N + col;
                const float a = acc[m][n][j];
                if constexpr (EPI == BEPI_NONE_BF) {
                    ((ushort*)Cm)[oi] = f2bf(a);
                } else if constexpr (EPI == BEPI_SILU_BF) {
                    ((ushort*)Cm)[oi] = f2bf(a / (1.f + __expf(-a)));
                } else if constexpr (EPI == BEPI_RELUSQ_BF) {
                    const float t = fmaxf(a, 0.f);
                    ((ushort*)Cm)[oi] = f2bf(t * t);
                } else if constexpr (EPI == BEPI_NONE_F) {
                    ((float*)Cm)[oi] = a;
                } else if constexpr (EPI == BEPI_RES_F) {
                    ((float*)Cm)[oi] = aux1[oi] + a;
                } else if constexpr (EPI == BEPI_SIGRES_F) {
                    ((float*)Cm)[oi] = aux1[oi] + aux2[oi] / (1.f + __expf(-a));
                } else if constexpr (EPI == BEPI_SIGRES2_F) {
                    const float kv = bf2f(((const ushort*)aux2)[oi]) +
                                     bf2f(((const ushort*)aux3)[oi]);
                    ((float*)Cm)[oi] = aux1[oi] + kv / (1.f + __expf(-a));
                } else if constexpr (EPI == BEPI_TANH_F) {
                    ((float*)Cm)[oi] = tanhf(a);
                } else if constexpr (EPI == BEPI_TANH_BF) {
                    ((ushort*)Cm)[oi] = f2bf(tanhf(a));
                } else {  // BEPI_DECAY_F
                    ((float*)Cm)[oi] = __expf(-__expf(a + aux1[col]));
                }
            }
        }
    }
}

// -------- Wcv split-K=2: z = K-half; bf16 partials to P0/P1 --------
__global__ __launch_bounds__(512) void wcv_kernel(const ushort* __restrict__ A,
                                                  const ushort* __restrict__ Bt,
                                                  ushort* __restrict__ P0,
                                                  ushort* __restrict__ P1)
{
    __shared__ GemmLds<64> lds;
    const int z = blockIdx.z;
    int w = blockIdx.y * gridDim.x + blockIdx.x;   // 16x16 = 256
    w = (w & 7) * 32 + (w >> 3);                    // XCD swizzle
    const int bn = (w % 16) * 64;
    const int bm = (w / 16) * 128;
    const int tid = threadIdx.x;
    const int wid = tid >> 6, lane = tid & 63;
    const int wr = wid >> 2, wc = wid & 3;
    const int l15 = lane & 15, lhi = lane >> 4;

    floatx4 acc[4][1];
#pragma unroll
    for (int m = 0; m < 4; ++m) acc[m][0] = (floatx4){0.f, 0.f, 0.f, 0.f};

    gemm_body8<64>(A + z * (FF / 2), Bt + z * (FF / 2), bm, bn, FF / 2, FF, FF, lds, acc);

    ushort* __restrict__ P = z ? P1 : P0;
#pragma unroll
    for (int m = 0; m < 4; ++m) {
        const int row0 = bm + wr * 64 + m * 16 + lhi * 4;
        const int col = bn + wc * 16 + l15;
#pragma unroll
        for (int j = 0; j < 4; ++j)
            P[(size_t)(row0 + j) * C + col] = f2bf(acc[m][0][j]);
    }
}

// -------- batched QKVG GEMM (BN=128): blockIdx.z selects {k,v,r,g} --------
struct QkvgArgs { const ushort* A[4]; ushort* O[4]; };
__global__ __launch_bounds__(512) void qkvg_kernel(QkvgArgs args,
                                                   const ushort* __restrict__ Wt)
{
    __shared__ GemmLds<128> lds;
    const int z = blockIdx.z;
    int w = blockIdx.y * gridDim.x + blockIdx.x;          // 8 x 16 grid = 128
    w = (w & 7) * 16 + (w >> 3);                           // XCD swizzle
    const int bn = (w & 7) * 128;
    const int bm = (w >> 3) * 128;
    const int tid = threadIdx.x;
    const int wid = tid >> 6, lane = tid & 63;
    const int wr = wid >> 2, wc = wid & 3;
    const int l15 = lane & 15, lhi = lane >> 4;

    floatx4 acc[4][2];
#pragma unroll
    for (int m = 0; m < 4; ++m)
#pragma unroll
        for (int n = 0; n < 2; ++n) acc[m][n] = (floatx4){0.f, 0.f, 0.f, 0.f};

    gemm_body8<128>(args.A[z], Wt + (size_t)z * C * C, bm, bn, C, C, C, lds, acc);

    ushort* __restrict__ O = args.O[z];
    const bool silu = (z == 3);
#pragma unroll
    for (int m = 0; m < 4; ++m) {
        const int row0 = bm + wr * 64 + m * 16 + lhi * 4;
#pragma unroll
        for (int n = 0; n < 2; ++n) {
            const int col = bn + wc * 32 + n * 16 + l15;
#pragma unroll
            for (int j = 0; j < 4; ++j) {
                float a = acc[m][n][j];
                if (silu) a = a / (1.f + __expf(-a));
                O[(size_t)(row0 + j) * C + col] = f2bf(a);
            }
        }
    }
}

// ---------------- launch ----------------
extern "C" void kernel_launch(void* const* d_in, const int* in_sizes, int n_in,
                              void* d_out, int out_size, void* d_ws, size_t ws_size,
                              hipStream_t stream)
{
    const float* x        = (const float*)d_in[0];
    const float* ln1_g    = (const float*)d_in[1];
    const float* ln1_b    = (const float*)d_in[2];
    const float* ln2_g    = (const float*)d_in[3];
    const float* ln2_b    = (const float*)d_in[4];
    const float* maa_x    = (const float*)d_in[5];
    const float* maa_w    = (const float*)d_in[6];
    const float* maa_k    = (const float*)d_in[7];
    const float* maa_v    = (const float*)d_in[8];
    const float* maa_r    = (const float*)d_in[9];
    const float* maa_g    = (const float*)d_in[10];
    const float* maa_w1   = (const float*)d_in[11];
    const float* maa_w2   = (const float*)d_in[12];
    const float* time_dec = (const float*)d_in[13];
    const float* tdw1     = (const float*)d_in[14];
    const float* tdw2     = (const float*)d_in[15];
    const float* u        = (const float*)d_in[16];
    const float* Wr       = (const float*)d_in[17];
    const float* Wk       = (const float*)d_in[18];
    const float* Wv       = (const float*)d_in[19];
    const float* Wg       = (const float*)d_in[20];
    const float* Wo       = (const float*)d_in[21];
    const float* lnx_g    = (const float*)d_in[22];
    const float* lnx_b    = (const float*)d_in[23];
    const float* cmaa_k   = (const float*)d_in[24];
    const float* cmaa_r   = (const float*)d_in[25];
    const float* Wck      = (const float*)d_in[26];
    const float* Wcv      = (const float*)d_in[27];
    const float* Wcr      = (const float*)d_in[28];
    float* out = (float*)d_out;

    // -------- workspace layout (~63 MB) --------
    float* fws = (float*)d_ws;
    const size_t E = (size_t)BT * C;            // 2,097,152
    float* xa  = fws + 0 * E;                   // xab+xxb bf16 ; yfb/ybb ; kk low
    float* xx  = fws + 1 * E;                   // kk high half
    float* wd  = fws + 2 * E;                   // decay d ; (FFN) Wcv bf16
    float* fs  = fws + 3 * E;                   // xvb/xrb ; M low ; kv partials
    ushort* wBuf = (ushort*)(fws + 4 * E);      // 4M ushort: weights / M high
    ushort* Mbuf = (ushort*)fs;                 // 2048*4096 bf16 = fs..wBuf (16MB)
    ushort* w2t  = wBuf + (size_t)C * 160;      // 5*C*32
    ushort* t1wt = wBuf + (size_t)C * 320;      // tdw1t [64 rows][C]
    ushort* t2wt = wBuf + (size_t)C * 384;      // tdw2t [C rows][64]
    ushort* bf1  = wBuf + (size_t)C * FF;       // E: ax / xkb / ck_in
    ushort* rb   = bf1 + E;                     // r ; (FFN) Wcr bf16
    ushort* kb   = rb + E;                      // k ; (FFN) Wo bf16
    ushort* vb   = kb + E;                      // v  -> ya
    ushort* gb   = vb + E;                      // g  -> cr_in
    ushort* t1b  = gb + E;                      // BT*64 bf16
    float* a5    = (float*)(t1b + (size_t)BT * 64);   // BT*160 (a5b bf16 inside)
    float* sig   = a5 + (size_t)BT * 160;       // (unused)
    float* Dbuf  = sig + (size_t)BT * H;        // 2048*64 f32
    ushort* a5b  = (ushort*)a5;                 // BT*160 bf16
    ushort* xvb  = (ushort*)fs;                 // E (mix v input)
    ushort* xrb  = (ushort*)fs + E;             // E (mix r input)
    ushort* xgb  = (ushort*)out;                // E (mix g input; out is scratch)
    ushort* xwb  = (ushort*)out + E;            // E (mix w input)
    ushort* xab  = (ushort*)xa;                 // E bf16 (LN output)
    ushort* xxb  = (ushort*)xa + E;             // E bf16 (shift delta)
    ushort* yfb  = (ushort*)xa;                 // E bf16 (forward y)
    ushort* ybb  = (ushort*)xa + E;             // E bf16 (backward y)
    ushort* p0b  = (ushort*)fs;                 // E bf16 (kv partial 0)
    ushort* p1b  = (ushort*)fs + E;             // E bf16 (kv partial 1)
    ushort* kk   = (ushort*)xa;                 // BT*FF bf16 == xa..xx
    ushort* wcvb = (ushort*)wd;                 // C*FF bf16 (Wcv, FFN phase)

    const dim3 blk(256);
    const dim3 gblk(512);
    const dim3 tblk(32, 8);
    const dim3 gNN(C / 64, BT / 128);

    // ---- early weight conversions: one launch (8 jobs, 448 tiles) ----
    WJobs ej;
    ej.njobs = 8;
    ej.W[0] = maa_w1; ej.dst[0] = wBuf; ej.Kd[0] = C; ej.Nd[0] = 160; ej.ntx[0] = 5; ej.base[0] = 0;
    for (int f = 0; f < 5; ++f) {
        ej.W[1 + f] = maa_w2 + (size_t)f * 32 * C;
        ej.dst[1 + f] = w2t + (size_t)f * C * 32;
        ej.Kd[1 + f] = 32; ej.Nd[1 + f] = C; ej.ntx[1 + f] = 32;
        ej.base[1 + f] = 160 + f * 32;
    }
    ej.W[6] = tdw1; ej.dst[6] = t1wt; ej.Kd[6] = C; ej.Nd[6] = 64; ej.ntx[6] = 2; ej.base[6] = 320;
    ej.W[7] = tdw2; ej.dst[7] = t2wt; ej.Kd[7] = 64; ej.Nd[7] = C; ej.ntx[7] = 32; ej.base[7] = 384;
    wconvB_kernel<<<dim3(448), tblk, 0, stream>>>(ej);

    // ---- attention branch ----
    lnshiftmix_kernel<<<BT, blk, 0, stream>>>(x, ln1_g, ln1_b, maa_x, xab, xxb, bf1);
    bgemm_kernel<64, BEPI_TANH_BF><<<dim3(3, BT / 128), gblk, 0, stream>>>(bf1, wBuf, a5b, BT, 160, C, nullptr, nullptr, nullptr);

    // all 5 mixes as one fused MFMA GEMM launch
    Mix5Args margs;
    margs.maa[0] = maa_w; margs.maa[1] = maa_k; margs.maa[2] = maa_v;
    margs.maa[3] = maa_r; margs.maa[4] = maa_g;
    margs.out[0] = xwb; margs.out[1] = bf1; margs.out[2] = xvb;
    margs.out[3] = xrb; margs.out[4] = xgb;
    mix5m_kernel<<<dim3(C / 64, BT / 128, 5), blk, 0, stream>>>(a5b, w2t, xab, xxb, margs);

    // w path: tanh(xw@tdw1) -> decay d = exp(-exp(@tdw2 + time_decay))
    bgemm_kernel<64, BEPI_TANH_BF><<<dim3(1, BT / 128), gblk, 0, stream>>>(xwb, t1wt, t1b, BT, 64, C, nullptr, nullptr, nullptr);
    bgemm_kernel<64, BEPI_DECAY_F><<<gNN, gblk, 0, stream>>>(t1b, t2wt, wd, BT, C, 64, time_dec, nullptr, nullptr);

    // batched QKVG
    Wconv4Args wargs;
    wargs.W[0] = Wk; wargs.W[1] = Wv; wargs.W[2] = Wr; wargs.W[3] = Wg;
    wconv4_kernel<<<dim3(C / 32, C / 32, 4), tblk, 0, stream>>>(wargs, wBuf);
    QkvgArgs qargs;
    qargs.A[0] = bf1; qargs.A[1] = xvb; qargs.A[2] = xrb; qargs.A[3] = xgb;
    qargs.O[0] = kb;  qargs.O[1] = vb;  qargs.O[2] = rb;  qargs.O[3] = gb;
    qkvg_kernel<<<dim3(8, 16, 4), gblk, 0, stream>>>(qargs, wBuf);

    // chunked bidirectional WKV (Mbuf overlays fs+wBuf; yfb/ybb overlay xa)
    wkv_pass1<<<dim3(2 * B * H * NCH), blk, 0, stream>>>(kb, vb, wd, Mbuf, Dbuf);
    wkv_pass2<<<dim3(2 * B * H), dim3(1024), 0, stream>>>(Mbuf, Dbuf);
    wkv_ymfma<<<dim3(2 * B * H * NCH), blk, 0, stream>>>(rb, kb, vb, wd, Mbuf, yfb, ybb);

    // ya = groupnorm(yf+yb+sig*v)*g
    gnmul_kernel<<<BT, dim3(1024), 0, stream>>>(yfb, ybb, lnx_g, lnx_b, gb, vb, rb, kb, u, vb);

    // ---- mega weight conversion (Wo->kb, Wck->wBuf, Wcv->wd, Wcr->rb) ----
    WJobs mj;
    mj.njobs = 4;
    mj.W[0] = Wo;  mj.dst[0] = kb;   mj.Kd[0] = C;  mj.Nd[0] = C;  mj.ntx[0] = 32;  mj.base[0] = 0;
    mj.W[1] = Wck; mj.dst[1] = wBuf; mj.Kd[1] = C;  mj.Nd[1] = FF; mj.ntx[1] = 128; mj.base[1] = 1024;
    mj.W[2] = Wcv; mj.dst[2] = wcvb; mj.Kd[2] = FF; mj.Nd[2] = C;  mj.ntx[2] = 32;  mj.base[2] = 5120;
    mj.W[3] = Wcr; mj.dst[3] = rb;   mj.Kd[3] = C;  mj.Nd[3] = C;  mj.ntx[3] = 32;  mj.base[3] = 9216;
    for (int i = 4; i < 8; ++i) { mj.W[i] = nullptr; mj.dst[i] = nullptr; mj.Kd[i] = 1; mj.Nd[i] = 1; mj.ntx[i] = 1; mj.base[i] = 1 << 30; }
    wconvB_kernel<<<dim3(10240), tblk, 0, stream>>>(mj);

    // out = x + ya @ Wo^T
    bgemm_kernel<64, BEPI_RES_F><<<gNN, gblk, 0, stream>>>(vb, kb, out, BT, C, C, x, nullptr, nullptr);

    // ---- FFN branch ----
    lnshiftcmix_kernel<<<BT, blk, 0, stream>>>(out, ln2_g, ln2_b, cmaa_k, cmaa_r, bf1, gb);
    bgemm_kernel<128, BEPI_RELUSQ_BF><<<dim3(FF / 128, BT / 128), gblk, 0, stream>>>(bf1, wBuf, kk, BT, FF, C, nullptr, nullptr, nullptr);
    wcv_kernel<<<dim3(16, 16, 2), gblk, 0, stream>>>(kk, wcvb, p0b, p1b);
    bgemm_kernel<64, BEPI_SIGRES2_F><<<gNN, gblk, 0, stream>>>(gb, rb, out, BT, C, C, out, (const float*)p0b, (const float*)p1b);

    (void)in_sizes; (void)n_in; (void)out_size; (void)ws_size;
}

// Round 18
// 232.995 us; speedup vs baseline: 1.0041x; 1.0041x over previous
//
#include <hip/hip_runtime.h>
#include <math.h>
#include <stdint.h>

static constexpr int B  = 8;
static constexpr int T  = 256;
static constexpr int C  = 1024;
static constexpr int H  = 16;
static constexpr int HEAD = 64;
static constexpr int FF = 4096;
static constexpr int BT = B * T;
static constexpr int NCH = 8;       // time chunks
static constexpr int CS  = 32;      // chunk size (NCH*CS == T)

typedef short short8  __attribute__((ext_vector_type(8)));
typedef float floatx4 __attribute__((ext_vector_type(4)));

// ---------------- bf16 helpers ----------------
__device__ __forceinline__ float bf2f(ushort u) {
    return __uint_as_float(((uint32_t)u) << 16);
}
__device__ __forceinline__ ushort f2bf(float x) {
    uint32_t u = __float_as_uint(x);
    u += 0x7fff + ((u >> 16) & 1);          // RNE
    return (ushort)(u >> 16);
}

__device__ __forceinline__ void gload16(const void* g, void* l) {
    __builtin_amdgcn_global_load_lds(
        (const __attribute__((address_space(1))) unsigned int*)g,
        (__attribute__((address_space(3))) unsigned int*)l, 16, 0, 0);
}

// ---------------- epilogue ids ----------------
#define BEPI_NONE_BF   0
#define BEPI_SILU_BF   1
#define BEPI_RELUSQ_BF 2
#define BEPI_NONE_F    3
#define BEPI_RES_F     4
#define BEPI_SIGRES_F  5
#define BEPI_TANH_F    6
#define BEPI_TANH_BF   7
#define BEPI_DECAY_F   8
#define BEPI_SIGRES2_F 9

// ---- 3-row LN helper: reduce 6 partial sums across block ----
__device__ __forceinline__ void red6(float (&vals)[6], float* red)
{
    const int wave = threadIdx.x >> 6, lane = threadIdx.x & 63;
#pragma unroll
    for (int i = 0; i < 6; ++i) {
        float v = vals[i];
#pragma unroll
        for (int off = 32; off > 0; off >>= 1) v += __shfl_xor(v, off);
        if (lane == 0) red[i * 4 + wave] = v;
    }
    __syncthreads();
#pragma unroll
    for (int i = 0; i < 6; ++i)
        vals[i] = red[i * 4 + 0] + red[i * 4 + 1] + red[i * 4 + 2] + red[i * 4 + 3];
}

// ---- fused LN + bshift + mixax (attention); xa/xx now bf16 ----
__global__ __launch_bounds__(256) void lnshiftmix_kernel(const float* __restrict__ x,
                                                         const float* __restrict__ g,
                                                         const float* __restrict__ b,
                                                         const float* __restrict__ maa,
                                                         ushort* __restrict__ xa,
                                                         ushort* __restrict__ xx,
                                                         ushort* __restrict__ ax)
{
    const int row = blockIdx.x;
    const int t = row & (T - 1);
    const int tid = threadIdx.x;
    __shared__ float red[24];
    const float4 vc = reinterpret_cast<const float4*>(x + (size_t)row * C)[tid];
    float4 vp = make_float4(0.f, 0.f, 0.f, 0.f), vn = make_float4(0.f, 0.f, 0.f, 0.f);
    if (t > 0)     vp = reinterpret_cast<const float4*>(x + (size_t)(row - 1) * C)[tid];
    if (t < T - 1) vn = reinterpret_cast<const float4*>(x + (size_t)(row + 1) * C)[tid];
    float vals[6];
    vals[0] = vc.x + vc.y + vc.z + vc.w;
    vals[1] = vc.x * vc.x + vc.y * vc.y + vc.z * vc.z + vc.w * vc.w;
    vals[2] = vp.x + vp.y + vp.z + vp.w;
    vals[3] = vp.x * vp.x + vp.y * vp.y + vp.z * vp.z + vp.w * vp.w;
    vals[4] = vn.x + vn.y + vn.z + vn.w;
    vals[5] = vn.x * vn.x + vn.y * vn.y + vn.z * vn.z + vn.w * vn.w;
    red6(vals, red);
    const float mc = vals[0] * (1.f / C);
    const float rc = rsqrtf(fmaxf(vals[1] * (1.f / C) - mc * mc, 0.f) + 1e-5f);
    const float mp = vals[2] * (1.f / C);
    const float rp = rsqrtf(fmaxf(vals[3] * (1.f / C) - mp * mp, 0.f) + 1e-5f);
    const float mn = vals[4] * (1.f / C);
    const float rn = rsqrtf(fmaxf(vals[5] * (1.f / C) - mn * mn, 0.f) + 1e-5f);

    const int c = tid * 4;
    const bool fh = ((c & 63) < 32);
    const float cur[4] = {vc.x, vc.y, vc.z, vc.w};
    const float nbr[4] = {fh ? vp.x : vn.x, fh ? vp.y : vn.y,
                          fh ? vp.z : vn.z, fh ? vp.w : vn.w};
    const float mN = fh ? mp : mn, rN = fh ? rp : rn;
    const bool nvalid = fh ? (t > 0) : (t < T - 1);
    const size_t rb = (size_t)row * C;
#pragma unroll
    for (int e = 0; e < 4; ++e) {
        const float gg = g[c + e], bb = b[c + e];
        const float av = (cur[e] - mc) * rc * gg + bb;
        const float sv = nvalid ? ((nbr[e] - mN) * rN * gg + bb) : 0.f;
        const float xv = sv - av;
        xa[rb + c + e] = f2bf(av);
        xx[rb + c + e] = f2bf(xv);
        ax[rb + c + e] = f2bf(av + xv * maa[c + e]);
    }
}

// ---- fused LN + bshift + cmix (FFN) ----
__global__ __launch_bounds__(256) void lnshiftcmix_kernel(const float* __restrict__ x,
                                                          const float* __restrict__ g,
                                                          const float* __restrict__ b,
                                                          const float* __restrict__ mk,
                                                          const float* __restrict__ mr,
                                                          ushort* __restrict__ ok,
                                                          ushort* __restrict__ orr)
{
    const int row = blockIdx.x;
    const int t = row & (T - 1);
    const int tid = threadIdx.x;
    __shared__ float red[24];
    const float4 vc = reinterpret_cast<const float4*>(x + (size_t)row * C)[tid];
    float4 vp = make_float4(0.f, 0.f, 0.f, 0.f), vn = make_float4(0.f, 0.f, 0.f, 0.f);
    if (t > 0)     vp = reinterpret_cast<const float4*>(x + (size_t)(row - 1) * C)[tid];
    if (t < T - 1) vn = reinterpret_cast<const float4*>(x + (size_t)(row + 1) * C)[tid];
    float vals[6];
    vals[0] = vc.x + vc.y + vc.z + vc.w;
    vals[1] = vc.x * vc.x + vc.y * vc.y + vc.z * vc.z + vc.w * vc.w;
    vals[2] = vp.x + vp.y + vp.z + vp.w;
    vals[3] = vp.x * vp.x + vp.y * vp.y + vp.z * vp.z + vp.w * vp.w;
    vals[4] = vn.x + vn.y + vn.z + vn.w;
    vals[5] = vn.x * vn.x + vn.y * vn.y + vn.z * vn.z + vn.w * vn.w;
    red6(vals, red);
    const float mc = vals[0] * (1.f / C);
    const float rc = rsqrtf(fmaxf(vals[1] * (1.f / C) - mc * mc, 0.f) + 1e-5f);
    const float mp = vals[2] * (1.f / C);
    const float rp = rsqrtf(fmaxf(vals[3] * (1.f / C) - mp * mp, 0.f) + 1e-5f);
    const float mn = vals[4] * (1.f / C);
    const float rn = rsqrtf(fmaxf(vals[5] * (1.f / C) - mn * mn, 0.f) + 1e-5f);

    const int c = tid * 4;
    const bool fh = ((c & 63) < 32);
    const float cur[4] = {vc.x, vc.y, vc.z, vc.w};
    const float nbr[4] = {fh ? vp.x : vn.x, fh ? vp.y : vn.y,
                          fh ? vp.z : vn.z, fh ? vp.w : vn.w};
    const float mN = fh ? mp : mn, rN = fh ? rp : rn;
    const bool nvalid = fh ? (t > 0) : (t < T - 1);
    const size_t rb = (size_t)row * C;
#pragma unroll
    for (int e = 0; e < 4; ++e) {
        const float gg = g[c + e], bb = b[c + e];
        const float av = (cur[e] - mc) * rc * gg + bb;
        const float sv = nvalid ? ((nbr[e] - mN) * rN * gg + bb) : 0.f;
        const float xv = sv - av;
        ok[rb + c + e]  = f2bf(av + xv * mk[c + e]);
        orr[rb + c + e] = f2bf(av + xv * mr[c + e]);
    }
}

// -------- GroupNorm(yf+yb+sig*v)*g+b, * gate; u-bonus scalar fused ---------
__global__ __launch_bounds__(1024) void gnmul_kernel(const ushort* __restrict__ yf,
                                                     const ushort* __restrict__ yb,
                                                     const float* __restrict__ g,
                                                     const float* __restrict__ b,
                                                     const ushort* __restrict__ gate,
                                                     const ushort* __restrict__ vin,
                                                     const ushort* __restrict__ rbuf,
                                                     const ushort* __restrict__ kbuf,
                                                     const float* __restrict__ u,
                                                     ushort* __restrict__ out)
{
    const int row = blockIdx.x;
    const int tid = threadIdx.x;                 // wave == head
    const size_t idx = (size_t)row * C + tid;
    float p = bf2f(rbuf[idx]) * bf2f(kbuf[idx]) * u[tid];
#pragma unroll
    for (int off = 32; off > 0; off >>= 1) p += __shfl_xor(p, off);
    const float v = bf2f(yf[idx]) + bf2f(yb[idx]) + p * bf2f(vin[idx]);
    float s = v;
#pragma unroll
    for (int off = 32; off > 0; off >>= 1) s += __shfl_xor(s, off);
    const float m = s * (1.0f / HEAD);
    const float d = v - m;
    float q = d * d;
#pragma unroll
    for (int off = 32; off > 0; off >>= 1) q += __shfl_xor(q, off);
    const float rstd = rsqrtf(q * (1.0f / HEAD) + 6.4e-4f);
    out[idx] = f2bf((d * rstd * g[tid] + b[tid]) * bf2f(gate[idx]));
}

// -------- batched weight convert+transpose: up to 8 jobs, one launch --------
struct WJobs {
    const float* W[8];
    ushort* dst[8];
    int Kd[8], Nd[8], ntx[8], base[8];
    int njobs;
};
__global__ __launch_bounds__(256) void wconvB_kernel(WJobs jobs)
{
    __shared__ float tile[32][33];
    const int bid = blockIdx.x;
    int j = 0;
#pragma unroll
    for (int i = 1; i < 8; ++i)
        if (i < jobs.njobs && bid >= jobs.base[i]) j = i;
    const float* __restrict__ W = jobs.W[j];
    ushort* __restrict__ dst = jobs.dst[j];
    const int Kd = jobs.Kd[j], Nd = jobs.Nd[j];
    const int local = bid - jobs.base[j];
    const int n0 = (local % jobs.ntx[j]) * 32;
    const int k0 = (local / jobs.ntx[j]) * 32;
    const int tx = threadIdx.x, ty = threadIdx.y;
#pragma unroll
    for (int i = 0; i < 4; ++i)
        tile[ty * 4 + i][tx] = W[(size_t)(k0 + ty * 4 + i) * Nd + n0 + tx];
    __syncthreads();
#pragma unroll
    for (int i = 0; i < 4; ++i)
        dst[(size_t)(n0 + ty * 4 + i) * Kd + k0 + tx] = f2bf(tile[tx][ty * 4 + i]);
}

// -------- batched wconv: 4 C x C weights (blockIdx.z) --------
struct Wconv4Args { const float* W[4]; };
__global__ __launch_bounds__(256) void wconv4_kernel(Wconv4Args args, ushort* __restrict__ Wt)
{
    __shared__ float tile[32][33];
    const int z = blockIdx.z;
    const float* __restrict__ W = args.W[z];
    ushort* __restrict__ dst = Wt + (size_t)z * C * C;
    const int n0 = blockIdx.x * 32, k0 = blockIdx.y * 32;
    const int tx = threadIdx.x, ty = threadIdx.y;
#pragma unroll
    for (int i = 0; i < 4; ++i)
        tile[ty * 4 + i][tx] = W[(size_t)(k0 + ty * 4 + i) * C + n0 + tx];
    __syncthreads();
#pragma unroll
    for (int i = 0; i < 4; ++i)
        dst[(size_t)(n0 + ty * 4 + i) * C + k0 + tx] = f2bf(tile[tx][ty * 4 + i]);
}

// ======== mix5 as fused MFMA GEMM (xa/xx bf16) ========
struct Mix5Args { const float* maa[5]; ushort* out[5]; };
__global__ __launch_bounds__(256) void mix5m_kernel(const ushort* __restrict__ a5b,
                                                    const ushort* __restrict__ w2t,
                                                    const ushort* __restrict__ xa,
                                                    const ushort* __restrict__ xx,
                                                    Mix5Args args)
{
    __shared__ __align__(16) ushort As[128 * 32];
    __shared__ __align__(16) ushort Bs[64 * 32];
    const int f = blockIdx.z;
    const int bm = blockIdx.y * 128, bn = blockIdx.x * 64;
    const int tid = threadIdx.x;
    const int wid = tid >> 6, lane = tid & 63;
    const int wr = wid >> 1, wc = wid & 1;
    const int l15 = lane & 15, lhi = lane >> 4;

#pragma unroll
    for (int p = 0; p < 2; ++p) {
        const int lin = p * 256 + tid;
        const int row = lin >> 2;
        const int sp = (lin & 3) ^ ((row >> 1) & 3);
        gload16(a5b + (size_t)(bm + row) * 160 + f * 32 + sp * 8, &As[lin * 8]);
    }
    {
        const int lin = tid;
        const int n = lin >> 2;
        const int sp = (lin & 3) ^ ((n >> 1) & 3);
        gload16(w2t + ((size_t)f * C + bn + n) * 32 + sp * 8, &Bs[lin * 8]);
    }
    __syncthreads();

    short8 af[4], bfr[2];
#pragma unroll
    for (int m = 0; m < 4; ++m) {
        const int row = wr * 64 + m * 16 + l15;
        const int sp = lhi ^ ((row >> 1) & 3);
        af[m] = *(const short8*)&As[row * 32 + sp * 8];
    }
#pragma unroll
    for (int n = 0; n < 2; ++n) {
        const int col = wc * 32 + n * 16 + l15;
        const int sp = lhi ^ ((col >> 1) & 3);
        bfr[n] = *(const short8*)&Bs[col * 32 + sp * 8];
    }
    floatx4 acc[4][2];
#pragma unroll
    for (int m = 0; m < 4; ++m)
#pragma unroll
        for (int n = 0; n < 2; ++n)
            acc[m][n] = __builtin_amdgcn_mfma_f32_16x16x32_bf16(
                af[m], bfr[n], (floatx4){0.f, 0.f, 0.f, 0.f}, 0, 0, 0);

    const float* __restrict__ maa = args.maa[f];
    ushort* __restrict__ out = args.out[f];
#pragma unroll
    for (int m = 0; m < 4; ++m) {
        const int row0 = bm + wr * 64 + m * 16 + lhi * 4;
#pragma unroll
        for (int n = 0; n < 2; ++n) {
            const int col = bn + wc * 32 + n * 16 + l15;
            const float mc = maa[col];
#pragma unroll
            for (int j = 0; j < 4; ++j) {
                const size_t oi = (size_t)(row0 + j) * C + col;
                out[oi] = f2bf(bf2f(xa[oi]) + bf2f(xx[oi]) * (mc + acc[m][n][j]));
            }
        }
    }
}

// ================== chunked bidirectional WKV6 (MFMA) ==================
__global__ __launch_bounds__(256) void wkv_pass1(const ushort* __restrict__ k,
                                                 const ushort* __restrict__ v,
                                                 const float* __restrict__ d,
                                                 ushort* __restrict__ M,
                                                 float* __restrict__ D)
{
    const int uc = blockIdx.x;
    const int c = uc & (NCH - 1), unit = uc >> 3;
    const int dir = unit & 1, bh = unit >> 1;
    const int tid = threadIdx.x;
    const int wv = tid >> 6, lane = tid & 63;
    const int l15 = lane & 15, lhi = lane >> 4;
    const size_t rowb = ((size_t)(bh >> 4) * T * H + (bh & 15)) * HEAD;
    const int s0 = c * CS;

    __shared__ ushort kT[64][40];
    __shared__ ushort vt[64][40];
    __shared__ float  Ldd[CS][64];

    for (int idx = tid; idx < CS * 64; idx += 256) {
        const int s = idx >> 6, j = idx & 63;
        const int t = dir ? (T - 1 - (s0 + s)) : (s0 + s);
        const size_t g = rowb + (size_t)t * (H * HEAD) + j;
        kT[j][s] = k[g];
        vt[j][s] = v[g];
        Ldd[s][j] = d[g];
    }
    __syncthreads();

    if (tid < 64) {
        const int j = tid;
        float G = 1.f;
#pragma unroll
        for (int s = CS - 1; s >= 0; --s) {
            kT[j][s] = f2bf(bf2f(kT[j][s]) * G);
            G *= Ldd[s][j];
        }
        D[(size_t)uc * 64 + j] = G;
    }
    __syncthreads();

    const short8 av = *(const short8*)&vt[wv * 16 + l15][lhi * 8];
    ushort* __restrict__ mrow = M + (size_t)uc * 4096;
#pragma unroll
    for (int n = 0; n < 4; ++n) {
        const short8 bk = *(const short8*)&kT[n * 16 + l15][lhi * 8];
        const floatx4 acc = __builtin_amdgcn_mfma_f32_16x16x32_bf16(
            av, bk, (floatx4){0.f, 0.f, 0.f, 0.f}, 0, 0, 0);
#pragma unroll
        for (int jr = 0; jr < 4; ++jr) {
            const int i = wv * 16 + lhi * 4 + jr;
            mrow[(size_t)i * 64 + n * 16 + l15] = f2bf(acc[jr]);
        }
    }
}

// pass2: prefetch all 8 chunk M/D values (independent), then 8 local steps.
__global__ __launch_bounds__(1024) void wkv_pass2(ushort* __restrict__ M,
                                                  const float* __restrict__ D)
{
    const int unit = blockIdx.x;
    const int tid = threadIdx.x;
    const int j0 = (tid & 15) * 4;
    uint2 mv[NCH];
    float4 Dv[NCH];
#pragma unroll
    for (int c = 0; c < NCH; ++c) {
        const int uc = unit * NCH + c;
        mv[c] = *reinterpret_cast<const uint2*>(M + (size_t)uc * 4096 + tid * 4);
        Dv[c] = *reinterpret_cast<const float4*>(D + (size_t)uc * 64 + j0);
    }
    float S0 = 0.f, S1 = 0.f, S2 = 0.f, S3 = 0.f;
#pragma unroll
    for (int c = 0; c < NCH; ++c) {
        const int uc = unit * NCH + c;
        uint2 sv;
        sv.x = (uint32_t)f2bf(S0) | ((uint32_t)f2bf(S1) << 16);
        sv.y = (uint32_t)f2bf(S2) | ((uint32_t)f2bf(S3) << 16);
        *reinterpret_cast<uint2*>(M + (size_t)uc * 4096 + tid * 4) = sv;
        S0 = fmaf(Dv[c].x, S0, bf2f((ushort)(mv[c].x & 0xffff)));
        S1 = fmaf(Dv[c].y, S1, bf2f((ushort)(mv[c].x >> 16)));
        S2 = fmaf(Dv[c].z, S2, bf2f((ushort)(mv[c].y & 0xffff)));
        S3 = fmaf(Dv[c].w, S3, bf2f((ushort)(mv[c].y >> 16)));
    }
}

__global__ __launch_bounds__(256) void wkv_ymfma(const ushort* __restrict__ r,
                                                 const ushort* __restrict__ k,
                                                 const ushort* __restrict__ v,
                                                 const float* __restrict__ d,
                                                 const ushort* __restrict__ Sin,
                                                 ushort* __restrict__ yf,
                                                 ushort* __restrict__ yb)
{
    const int uc = blockIdx.x;
    const int c = uc & (NCH - 1), unit = uc >> 3;
    const int dir = unit & 1, bh = unit >> 1;
    const int tid = threadIdx.x;
    const int wv = tid >> 6, lane = tid & 63;
    const int l15 = lane & 15, lhi = lane >> 4;
    const size_t rowb = ((size_t)(bh >> 4) * T * H + (bh & 15)) * HEAD;
    const int s0 = c * CS;

    __shared__ ushort rp[32][64];
    __shared__ ushort kp[32][64];
    __shared__ ushort vt[64][40];
    __shared__ ushort Pl[32][32];
    __shared__ float  Ldd[CS][64];

    for (int idx = tid; idx < 32 * 64; idx += 256) {
        const int s = idx >> 6, j = idx & 63;
        const int t = dir ? (T - 1 - (s0 + s)) : (s0 + s);
        const size_t g = rowb + (size_t)t * (H * HEAD) + j;
        const int cs = (j >> 3) ^ (s & 7);
        rp[s][cs * 8 + (j & 7)] = r[g];
        kp[s][cs * 8 + (j & 7)] = k[g];
        vt[j][s] = v[g];
        Ldd[s][j] = d[g];
    }
    __syncthreads();

    if (wv == 0) {                   // r' = r * Q[s]
        const int j = lane;
        float Q = 1.f;
#pragma unroll
        for (int s = 0; s < 32; ++s) {
            const int a = ((j >> 3) ^ (s & 7)) * 8 + (j & 7);
            rp[s][a] = f2bf(bf2f(rp[s][a]) * Q);
            Q *= Ldd[s][j];
        }
    } else if (wv == 1) {            // k' = k / Q[s+1]
        const int j = lane;
        float iQ = 1.f;
#pragma unroll
        for (int s = 0; s < 32; ++s) {
            iQ *= (1.0f / Ldd[s][j]);
            const int a = ((j >> 3) ^ (s & 7)) * 8 + (j & 7);
            kp[s][a] = f2bf(bf2f(kp[s][a]) * iQ);
        }
    }
    __syncthreads();

    const int st = wv & 1;
    const int ip = wv >> 1;

    short8 ar[2];
#pragma unroll
    for (int ks = 0; ks < 2; ++ks) {
        const int row = st * 16 + l15;
        const int ch = (ks * 4 + lhi) ^ (row & 7);
        ar[ks] = *(const short8*)&rp[row][ch * 8];
    }

    floatx4 acc[2];
#pragma unroll
    for (int n = 0; n < 2; ++n) {
        const int i = ip * 32 + n * 16 + l15;
        const ushort* sp = Sin + (size_t)uc * 4096 + (size_t)i * 64;
        const short8 b0 = *(const short8*)&sp[lhi * 8];
        const short8 b1 = *(const short8*)&sp[32 + lhi * 8];
        acc[n] = __builtin_amdgcn_mfma_f32_16x16x32_bf16(ar[0], b0, (floatx4){0.f, 0.f, 0.f, 0.f}, 0, 0, 0);
        acc[n] = __builtin_amdgcn_mfma_f32_16x16x32_bf16(ar[1], b1, acc[n], 0, 0, 0);
    }

    if (wv < 2) {
#pragma unroll
        for (int ut = 0; ut < 2; ++ut) {
            const int urow = ut * 16 + l15;
            const short8 bk0 = *(const short8*)&kp[urow][((0 + lhi) ^ (urow & 7)) * 8];
            const short8 bk1 = *(const short8*)&kp[urow][((4 + lhi) ^ (urow & 7)) * 8];
            floatx4 pa = __builtin_amdgcn_mfma_f32_16x16x32_bf16(ar[0], bk0, (floatx4){0.f, 0.f, 0.f, 0.f}, 0, 0, 0);
            pa = __builtin_amdgcn_mfma_f32_16x16x32_bf16(ar[1], bk1, pa, 0, 0, 0);
            const int sg0 = st * 16 + lhi * 4;
            const int ug = ut * 16 + l15;
#pragma unroll
            for (int jr = 0; jr < 4; ++jr) {
                const float val = (ug < sg0 + jr) ? pa[jr] : 0.f;
                Pl[sg0 + jr][ug] = f2bf(val);
            }
        }
    }
    __syncthreads();

    short8 ap;
    {
        const int row = st * 16 + l15;
        ap = *(const short8*)&Pl[row][lhi * 8];
    }
#pragma unroll
    for (int n = 0; n < 2; ++n) {
        const int i = ip * 32 + n * 16 + l15;
        const short8 bv = *(const short8*)&vt[i][lhi * 8];
        acc[n] = __builtin_amdgcn_mfma_f32_16x16x32_bf16(ap, bv, acc[n], 0, 0, 0);
    }

    ushort* __restrict__ yo = dir ? yb : yf;
#pragma unroll
    for (int n = 0; n < 2; ++n) {
        const int i = ip * 32 + n * 16 + l15;
#pragma unroll
        for (int jr = 0; jr < 4; ++jr) {
            const int sg = st * 16 + lhi * 4 + jr;
            const int t = dir ? (T - 1 - (s0 + sg)) : (s0 + sg);
            yo[rowb + (size_t)t * (H * HEAD) + i] = f2bf(acc[n][jr]);
        }
    }
}

// ======== pipelined bf16 MFMA GEMM core: 8 waves (512 thr), BM=128, BK=64 ======
template <int BN>
struct GemmLds {
    ushort As[2][128 * 64];
    ushort Bs[2][BN * 64];
};

template <int BN>
__device__ __forceinline__ void gemm_body8(const ushort* __restrict__ A,
                                           const ushort* __restrict__ Bt,
                                           int bm, int bn, int K, int lda, int ldb,
                                           GemmLds<BN>& lds,
                                           floatx4 (&acc)[4][BN / 64])
{
    constexpr int NF = BN / 64;
    const int tid = threadIdx.x;                 // 512
    const int wid = tid >> 6, lane = tid & 63;
    const int wr = wid >> 2, wc = wid & 3;
    const int l15 = lane & 15, lhi = lane >> 4;
    const int NT = K >> 6;

    auto stage = [&](int buf, int k0) {
#pragma unroll
        for (int p = 0; p < 2; ++p) {
            const int lin = p * 512 + tid;
            const int row = lin >> 3;
            const int cs = (lin & 7) ^ (row & 7);
            gload16(A + (size_t)(bm + row) * lda + k0 + cs * 8, &lds.As[buf][lin * 8]);
        }
#pragma unroll
        for (int p = 0; p < NF; ++p) {
            const int lin = p * 512 + tid;
            const int n = lin >> 3;
            const int cs = (lin & 7) ^ (n & 7);
            gload16(Bt + (size_t)(bn + n) * ldb + k0 + cs * 8, &lds.Bs[buf][lin * 8]);
        }
    };

    stage(0, 0);
    __syncthreads();
    for (int t = 0; t < NT; ++t) {
        const int cur = t & 1;
        if (t + 1 < NT) stage(cur ^ 1, (t + 1) << 6);

        short8 af[4][2];
#pragma unroll
        for (int m = 0; m < 4; ++m) {
            const int row = wr * 64 + m * 16 + l15;
#pragma unroll
            for (int s = 0; s < 2; ++s) {
                const int cc = (s * 4 + lhi) ^ (row & 7);
                af[m][s] = *(const short8*)&lds.As[cur][row * 64 + cc * 8];
            }
        }
        short8 bf[NF][2];
#pragma unroll
        for (int n = 0; n < NF; ++n) {
            const int col = wc * (BN / 4) + n * 16 + l15;
#pragma unroll
            for (int s = 0; s < 2; ++s) {
                const int cc = (s * 4 + lhi) ^ (col & 7);
                bf[n][s] = *(const short8*)&lds.Bs[cur][col * 64 + cc * 8];
            }
        }
#pragma unroll
        for (int m = 0; m < 4; ++m)
#pragma unroll
            for (int n = 0; n < NF; ++n) {
                acc[m][n] = __builtin_amdgcn_mfma_f32_16x16x32_bf16(af[m][0], bf[n][0], acc[m][n], 0, 0, 0);
                acc[m][n] = __builtin_amdgcn_mfma_f32_16x16x32_bf16(af[m][1], bf[n][1], acc[m][n], 0, 0, 0);
            }
        __syncthreads();
    }
}

template <int BN, int EPI>
__global__ __launch_bounds__(512) void bgemm_kernel(const ushort* __restrict__ A,
                                                    const ushort* __restrict__ Bt,
                                                    void* __restrict__ Cm,
                                                    int M, int N, int K,
                                                    const float* __restrict__ aux1,
                                                    const float* __restrict__ aux2,
                                                    const float* __restrict__ aux3)
{
    constexpr int NF = BN / 64;
    __shared__ GemmLds<BN> lds;
    int w = blockIdx.y * gridDim.x + blockIdx.x;
    const int nwg = gridDim.x * gridDim.y;
    if ((nwg & 7) == 0) w = (w & 7) * (nwg >> 3) + (w >> 3);   // XCD swizzle
    const int bn = (w % gridDim.x) * BN;
    const int bm = (w / gridDim.x) * 128;
    const int tid = threadIdx.x;
    const int wid = tid >> 6, lane = tid & 63;
    const int wr = wid >> 2, wc = wid & 3;
    const int l15 = lane & 15, lhi = lane >> 4;

    floatx4 acc[4][NF];
#pragma unroll
    for (int m = 0; m < 4; ++m)
#pragma unroll
        for (int n = 0; n < NF; ++n) acc[m][n] = (floatx4){0.f, 0.f, 0.f, 0.f};

    gemm_body8<BN>(A, Bt, bm, bn, K, K, K, lds, acc);

#pragma unroll
    for (int m = 0; m < 4; ++m) {
        const int row0 = bm + wr * 64 + m * 16 + lhi * 4;
#pragma unroll
        for (int n = 0; n < NF; ++n) {
            const int col = bn + wc * (BN / 4) + n * 16 + l15;
            if (col >= N) continue;
#pragma unroll
            for (int j = 0; j < 4; ++j) {
                const size_t oi = (size_t)(row0 + j) * N + col;
                const float a = acc[m][n][j];
                if constexpr (EPI == BEPI_NONE_BF) {
                    ((ushort*)Cm)[oi] = f2bf(a);
                } else if constexpr (EPI == BEPI_SILU_BF) {
                    ((ushort*)Cm)[oi] = f2bf(a / (1.f + __expf(-a)));
                } else if constexpr (EPI == BEPI_RELUSQ_BF) {
                    const float t = fmaxf(a, 0.f);
                    ((ushort*)Cm)[oi] = f2bf(t * t);
                } else if constexpr (EPI == BEPI_NONE_F) {
                    ((float*)Cm)[oi] = a;
                } else if constexpr (EPI == BEPI_RES_F) {
                    ((float*)Cm)[oi] = aux1[oi] + a;
                } else if constexpr (EPI == BEPI_SIGRES_F) {
                    ((float*)Cm)[oi] = aux1[oi] + aux2[oi] / (1.f + __expf(-a));
                } else if constexpr (EPI == BEPI_SIGRES2_F) {
                    const float kv = bf2f(((const ushort*)aux2)[oi]) +
                                     bf2f(((const ushort*)aux3)[oi]);
                    ((float*)Cm)[oi] = aux1[oi] + kv / (1.f + __expf(-a));
                } else if constexpr (EPI == BEPI_TANH_F) {
                    ((float*)Cm)[oi] = tanhf(a);
                } else if constexpr (EPI == BEPI_TANH_BF) {
                    ((ushort*)Cm)[oi] = f2bf(tanhf(a));
                } else {  // BEPI_DECAY_F
                    ((float*)Cm)[oi] = __expf(-__expf(a + aux1[col]));
                }
            }
        }
    }
}

// -------- Wcv split-K=2: z = K-half; bf16 partials to P0/P1 --------
__global__ __launch_bounds__(512) void wcv_kernel(const ushort* __restrict__ A,
                                                  const ushort* __restrict__ Bt,
                                                  ushort* __restrict__ P0,
                                                  ushort* __restrict__ P1)
{
    __shared__ GemmLds<64> lds;
    const int z = blockIdx.z;
    int w = blockIdx.y * gridDim.x + blockIdx.x;   // 16x16 = 256
    w = (w & 7) * 32 + (w >> 3);                    // XCD swizzle
    const int bn = (w % 16) * 64;
    const int bm = (w / 16) * 128;
    const int tid = threadIdx.x;
    const int wid = tid >> 6, lane = tid & 63;
    const int wr = wid >> 2, wc = wid & 3;
    const int l15 = lane & 15, lhi = lane >> 4;

    floatx4 acc[4][1];
#pragma unroll
    for (int m = 0; m < 4; ++m) acc[m][0] = (floatx4){0.f, 0.f, 0.f, 0.f};

    gemm_body8<64>(A + z * (FF / 2), Bt + z * (FF / 2), bm, bn, FF / 2, FF, FF, lds, acc);

    ushort* __restrict__ P = z ? P1 : P0;
#pragma unroll
    for (int m = 0; m < 4; ++m) {
        const int row0 = bm + wr * 64 + m * 16 + lhi * 4;
        const int col = bn + wc * 16 + l15;
#pragma unroll
        for (int j = 0; j < 4; ++j)
            P[(size_t)(row0 + j) * C + col] = f2bf(acc[m][0][j]);
    }
}

// -------- batched QKVG GEMM (BN=128): blockIdx.z selects {k,v,r,g} --------
struct QkvgArgs { const ushort* A[4]; ushort* O[4]; };
__global__ __launch_bounds__(512) void qkvg_kernel(QkvgArgs args,
                                                   const ushort* __restrict__ Wt)
{
    __shared__ GemmLds<128> lds;
    const int z = blockIdx.z;
    int w = blockIdx.y * gridDim.x + blockIdx.x;          // 8 x 16 grid = 128
    w = (w & 7) * 16 + (w >> 3);                           // XCD swizzle
    const int bn = (w & 7) * 128;
    const int bm = (w >> 3) * 128;
    const int tid = threadIdx.x;
    const int wid = tid >> 6, lane = tid & 63;
    const int wr = wid >> 2, wc = wid & 3;
    const int l15 = lane & 15, lhi = lane >> 4;

    floatx4 acc[4][2];
#pragma unroll
    for (int m = 0; m < 4; ++m)
#pragma unroll
        for (int n = 0; n < 2; ++n) acc[m][n] = (floatx4){0.f, 0.f, 0.f, 0.f};

    gemm_body8<128>(args.A[z], Wt + (size_t)z * C * C, bm, bn, C, C, C, lds, acc);

    ushort* __restrict__ O = args.O[z];
    const bool silu = (z == 3);
#pragma unroll
    for (int m = 0; m < 4; ++m) {
        const int row0 = bm + wr * 64 + m * 16 + lhi * 4;
#pragma unroll
        for (int n = 0; n < 2; ++n) {
            const int col = bn + wc * 32 + n * 16 + l15;
#pragma unroll
            for (int j = 0; j < 4; ++j) {
                float a = acc[m][n][j];
                if (silu) a = a / (1.f + __expf(-a));
                O[(size_t)(row0 + j) * C + col] = f2bf(a);
            }
        }
    }
}

// ---------------- launch ----------------
extern "C" void kernel_launch(void* const* d_in, const int* in_sizes, int n_in,
                              void* d_out, int out_size, void* d_ws, size_t ws_size,
                              hipStream_t stream)
{
    const float* x        = (const float*)d_in[0];
    const float* ln1_g    = (const float*)d_in[1];
    const float* ln1_b    = (const float*)d_in[2];
    const float* ln2_g    = (const float*)d_in[3];
    const float* ln2_b    = (const float*)d_in[4];
    const float* maa_x    = (const float*)d_in[5];
    const float* maa_w    = (const float*)d_in[6];
    const float* maa_k    = (const float*)d_in[7];
    const float* maa_v    = (const float*)d_in[8];
    const float* maa_r    = (const float*)d_in[9];
    const float* maa_g    = (const float*)d_in[10];
    const float* maa_w1   = (const float*)d_in[11];
    const float* maa_w2   = (const float*)d_in[12];
    const float* time_dec = (const float*)d_in[13];
    const float* tdw1     = (const float*)d_in[14];
    const float* tdw2     = (const float*)d_in[15];
    const float* u        = (const float*)d_in[16];
    const float* Wr       = (const float*)d_in[17];
    const float* Wk       = (const float*)d_in[18];
    const float* Wv       = (const float*)d_in[19];
    const float* Wg       = (const float*)d_in[20];
    const float* Wo       = (const float*)d_in[21];
    const float* lnx_g    = (const float*)d_in[22];
    const float* lnx_b    = (const float*)d_in[23];
    const float* cmaa_k   = (const float*)d_in[24];
    const float* cmaa_r   = (const float*)d_in[25];
    const float* Wck      = (const float*)d_in[26];
    const float* Wcv      = (const float*)d_in[27];
    const float* Wcr      = (const float*)d_in[28];
    float* out = (float*)d_out;

    // -------- workspace layout (~63 MB) --------
    float* fws = (float*)d_ws;
    const size_t E = (size_t)BT * C;            // 2,097,152
    float* xa  = fws + 0 * E;                   // xab+xxb bf16 ; yfb/ybb ; kk low
    float* xx  = fws + 1 * E;                   // kk high half
    float* wd  = fws + 2 * E;                   // decay d ; (FFN) Wcv bf16
    float* fs  = fws + 3 * E;                   // xvb/xrb ; M low ; kv partials
    ushort* wBuf = (ushort*)(fws + 4 * E);      // 4M ushort: weights / M high
    ushort* Mbuf = (ushort*)fs;                 // 2048*4096 bf16 = fs..wBuf (16MB)
    ushort* w2t  = wBuf + (size_t)C * 160;      // 5*C*32
    ushort* t1wt = wBuf + (size_t)C * 320;      // tdw1t [64 rows][C]
    ushort* t2wt = wBuf + (size_t)C * 384;      // tdw2t [C rows][64]
    ushort* bf1  = wBuf + (size_t)C * FF;       // E: ax / xkb / ck_in
    ushort* rb   = bf1 + E;                     // r ; (FFN) Wcr bf16
    ushort* kb   = rb + E;                      // k ; (FFN) Wo bf16
    ushort* vb   = kb + E;                      // v  -> ya
    ushort* gb   = vb + E;                      // g  -> cr_in
    ushort* t1b  = gb + E;                      // BT*64 bf16
    float* a5    = (float*)(t1b + (size_t)BT * 64);   // BT*160 (a5b bf16 inside)
    float* sig   = a5 + (size_t)BT * 160;       // (unused)
    float* Dbuf  = sig + (size_t)BT * H;        // 2048*64 f32
    ushort* a5b  = (ushort*)a5;                 // BT*160 bf16
    ushort* xvb  = (ushort*)fs;                 // E (mix v input)
    ushort* xrb  = (ushort*)fs + E;             // E (mix r input)
    ushort* xgb  = (ushort*)out;                // E (mix g input; out is scratch)
    ushort* xwb  = (ushort*)out + E;            // E (mix w input)
    ushort* xab  = (ushort*)xa;                 // E bf16 (LN output)
    ushort* xxb  = (ushort*)xa + E;             // E bf16 (shift delta)
    ushort* yfb  = (ushort*)xa;                 // E bf16 (forward y)
    ushort* ybb  = (ushort*)xa + E;             // E bf16 (backward y)
    ushort* p0b  = (ushort*)fs;                 // E bf16 (kv partial 0)
    ushort* p1b  = (ushort*)fs + E;             // E bf16 (kv partial 1)
    ushort* kk   = (ushort*)xa;                 // BT*FF bf16 == xa..xx
    ushort* wcvb = (ushort*)wd;                 // C*FF bf16 (Wcv, FFN phase)

    const dim3 blk(256);
    const dim3 gblk(512);
    const dim3 tblk(32, 8);
    const dim3 gNN(C / 64, BT / 128);

    // ---- early weight conversions: one launch (8 jobs, 448 tiles) ----
    WJobs ej;
    ej.njobs = 8;
    ej.W[0] = maa_w1; ej.dst[0] = wBuf; ej.Kd[0] = C; ej.Nd[0] = 160; ej.ntx[0] = 5; ej.base[0] = 0;
    for (int f = 0; f < 5; ++f) {
        ej.W[1 + f] = maa_w2 + (size_t)f * 32 * C;
        ej.dst[1 + f] = w2t + (size_t)f * C * 32;
        ej.Kd[1 + f] = 32; ej.Nd[1 + f] = C; ej.ntx[1 + f] = 32;
        ej.base[1 + f] = 160 + f * 32;
    }
    ej.W[6] = tdw1; ej.dst[6] = t1wt; ej.Kd[6] = C; ej.Nd[6] = 64; ej.ntx[6] = 2; ej.base[6] = 320;
    ej.W[7] = tdw2; ej.dst[7] = t2wt; ej.Kd[7] = 64; ej.Nd[7] = C; ej.ntx[7] = 32; ej.base[7] = 384;
    wconvB_kernel<<<dim3(448), tblk, 0, stream>>>(ej);

    // ---- attention branch ----
    lnshiftmix_kernel<<<BT, blk, 0, stream>>>(x, ln1_g, ln1_b, maa_x, xab, xxb, bf1);
    bgemm_kernel<64, BEPI_TANH_BF><<<dim3(3, BT / 128), gblk, 0, stream>>>(bf1, wBuf, a5b, BT, 160, C, nullptr, nullptr, nullptr);

    // all 5 mixes as one fused MFMA GEMM launch
    Mix5Args margs;
    margs.maa[0] = maa_w; margs.maa[1] = maa_k; margs.maa[2] = maa_v;
    margs.maa[3] = maa_r; margs.maa[4] = maa_g;
    margs.out[0] = xwb; margs.out[1] = bf1; margs.out[2] = xvb;
    margs.out[3] = xrb; margs.out[4] = xgb;
    mix5m_kernel<<<dim3(C / 64, BT / 128, 5), blk, 0, stream>>>(a5b, w2t, xab, xxb, margs);

    // w path: tanh(xw@tdw1) -> decay d = exp(-exp(@tdw2 + time_decay))
    bgemm_kernel<64, BEPI_TANH_BF><<<dim3(1, BT / 128), gblk, 0, stream>>>(xwb, t1wt, t1b, BT, 64, C, nullptr, nullptr, nullptr);
    bgemm_kernel<64, BEPI_DECAY_F><<<gNN, gblk, 0, stream>>>(t1b, t2wt, wd, BT, C, 64, time_dec, nullptr, nullptr);

    // batched QKVG
    Wconv4Args wargs;
    wargs.W[0] = Wk; wargs.W[1] = Wv; wargs.W[2] = Wr; wargs.W[3] = Wg;
    wconv4_kernel<<<dim3(C / 32, C / 32, 4), tblk, 0, stream>>>(wargs, wBuf);
    QkvgArgs qargs;
    qargs.A[0] = bf1; qargs.A[1] = xvb; qargs.A[2] = xrb; qargs.A[3] = xgb;
    qargs.O[0] = kb;  qargs.O[1] = vb;  qargs.O[2] = rb;  qargs.O[3] = gb;
    qkvg_kernel<<<dim3(8, 16, 4), gblk, 0, stream>>>(qargs, wBuf);

    // chunked bidirectional WKV (Mbuf overlays fs+wBuf; yfb/ybb overlay xa)
    wkv_pass1<<<dim3(2 * B * H * NCH), blk, 0, stream>>>(kb, vb, wd, Mbuf, Dbuf);
    wkv_pass2<<<dim3(2 * B * H), dim3(1024), 0, stream>>>(Mbuf, Dbuf);
    wkv_ymfma<<<dim3(2 * B * H * NCH), blk, 0, stream>>>(rb, kb, vb, wd, Mbuf, yfb, ybb);

    // ya = groupnorm(yf+yb+sig*v)*g
    gnmul_kernel<<<BT, dim3(1024), 0, stream>>>(yfb, ybb, lnx_g, lnx_b, gb, vb, rb, kb, u, vb);

    // ---- mega weight conversion (Wo->kb, Wck->wBuf, Wcv->wd, Wcr->rb) ----
    WJobs mj;
    mj.njobs = 4;
    mj.W[0] = Wo;  mj.dst[0] = kb;   mj.Kd[0] = C;  mj.Nd[0] = C;  mj.ntx[0] = 32;  mj.base[0] = 0;
    mj.W[1] = Wck; mj.dst[1] = wBuf; mj.Kd[1] = C;  mj.Nd[1] = FF; mj.ntx[1] = 128; mj.base[1] = 1024;
    mj.W[2] = Wcv; mj.dst[2] = wcvb; mj.Kd[2] = FF; mj.Nd[2] = C;  mj.ntx[2] = 32;  mj.base[2] = 5120;
    mj.W[3] = Wcr; mj.dst[3] = rb;   mj.Kd[3] = C;  mj.Nd[3] = C;  mj.ntx[3] = 32;  mj.base[3] = 9216;
    for (int i = 4; i < 8; ++i) { mj.W[i] = nullptr; mj.dst[i] = nullptr; mj.Kd[i] = 1; mj.Nd[i] = 1; mj.ntx[i] = 1; mj.base[i] = 1 << 30; }
    wconvB_kernel<<<dim3(10240), tblk, 0, stream>>>(mj);

    // out = x + ya @ Wo^T
    bgemm_kernel<64, BEPI_RES_F><<<gNN, gblk, 0, stream>>>(vb, kb, out, BT, C, C, x, nullptr, nullptr);

    // ---- FFN branch ----
    lnshiftcmix_kernel<<<BT, blk, 0, stream>>>(out, ln2_g, ln2_b, cmaa_k, cmaa_r, bf1, gb);
    bgemm_kernel<128, BEPI_RELUSQ_BF><<<dim3(FF / 128, BT / 128), gblk, 0, stream>>>(bf1, wBuf, kk, BT, FF, C, nullptr, nullptr, nullptr);
    wcv_kernel<<<dim3(16, 16, 2), gblk, 0, stream>>>(kk, wcvb, p0b, p1b);
    bgemm_kernel<64, BEPI_SIGRES2_F><<<gNN, gblk, 0, stream>>>(gb, rb, out, BT, C, C, out, (const float*)p0b, (const float*)p1b);

    (void)in_sizes; (void)n_in; (void)out_size; (void)ws_size;
}